// Round 13
// baseline (232.463 us; speedup 1.0000x reference)
//
#include <hip/hip_runtime.h>
#include <hip/hip_bf16.h>

// ---------- types / helpers ----------
typedef __attribute__((ext_vector_type(4))) float f32x4;   // MFMA C/D frag
typedef __attribute__((ext_vector_type(4))) int   int4v;   // one 16B load
typedef __attribute__((ext_vector_type(8))) int   int8v;   // K=128 fp8 A/B frag (32B)

// float -> OCP e4m3fn byte (RNE on normals, RN on subnormals, saturate to 448)
// (cold path: weight prep + GEMM epilogue; gather hot path uses HW v_cvt_pk_fp8_f32)
__device__ __forceinline__ unsigned char f2fp8(float f) {
    unsigned char s = (__float_as_uint(f) >> 24) & 0x80;
    float a = fabsf(f);
    if (a >= 448.f) return s | 0x7E;
    if (a < 0.015625f) {                       // subnormal: step 2^-9
        int q = (int)(a * 512.0f + 0.5f);
        return s | (unsigned char)q;
    }
    unsigned int u = __float_as_uint(a);
    u += 0x0007FFFF + ((u >> 20) & 1);         // RNE to 3 mantissa bits (carry-safe)
    int e8 = (int)((u >> 23) & 0xFF) - 120;    // -127+7
    if (e8 >= 16) return s | 0x7E;
    return s | (unsigned char)((e8 << 3) | ((u >> 20) & 7));
}
__device__ __forceinline__ void gload_lds16(const void* g, void* l) {
    // async global->LDS, 16B/lane; LDS dest = wave-uniform base + lane*16
    __builtin_amdgcn_global_load_lds((const __attribute__((address_space(1))) void*)g,
                                     (__attribute__((address_space(3))) void*)l, 16, 0, 0);
}

// ---------- constants ----------
#define BATCH 256
#define CHAN  768
#define HW    196
#define SPS   196
#define HID   512
#define MROWS 50176   // BATCH*SPS
#define K1    1536    // 2*CHAN
#define WSCL  64.0f           // weights pre-scaled by 64 (e4m3 subnormal dodge)
#define WINV  0.015625f       // 1/64 applied in epilogue
#define SC1   0x7F7F7F7F      // E8M0 scale 1.0 in every byte (mapping-invariant)

// ---------- weight prep: in [K][N] fp32 -> out [N][K] fp8 of (w * 64) ----------
__global__ void transpose_cast_fp8(const float* __restrict__ in, unsigned char* __restrict__ out,
                                   int K, int N) {
    int idx = blockIdx.x * 256 + threadIdx.x;
    if (idx >= K * N) return;
    int n = idx / K, k = idx - n * K;
    out[idx] = f2fp8(in[(size_t)k * N + n] * WSCL);
}

// ---------- gather + out-init: feats fp8 via HW cvt_pk; 4B packed stores (R11, proven) ----------
__global__ __launch_bounds__(256) void gather_feats(const float* __restrict__ x,
                                                    const int* __restrict__ pxs,
                                                    const int* __restrict__ pys,
                                                    const float* __restrict__ b3,
                                                    unsigned char* __restrict__ feats,
                                                    float* __restrict__ out) {
    __shared__ float lds[64 * 197];   // pitch 197: stride-5 banks, conflict-free
    int chunk = blockIdx.x;           // 0..11 (64-channel chunk)
    int b     = blockIdx.y;           // 0..255
    int c0 = chunk * 64;
    const float* xb = x + ((size_t)b * CHAN + c0) * HW;
    for (int t = threadIdx.x; t < 64 * HW; t += 256) {
        int j = t / HW, p = t - j * HW;
        lds[j * 197 + p] = xb[t];     // coalesced read of 64 full channels
    }
    if (chunk == 0) {                 // per-batch: init pred rows to b3, write deltaxy
        float b30 = b3[0], b31 = b3[1];
        for (int i = threadIdx.x; i < SPS * 2; i += 256) {
            int idx = b * SPS * 2 + i;
            out[idx] = (i & 1) ? b31 : b30;                          // pred init (atomics add on top)
            out[MROWS * 2 + idx] = (float)(pxs[idx] - pys[idx]) + 13.0f;  // (H-1)=13
        }
    }
    __syncthreads();
    int wid = threadIdx.x >> 6, lane = threadIdx.x & 63;
    int g = lane >> 4;                // s-offset within the 4-s pack
    int cq = (lane & 15) * 4;         // channel quad 0,4,..,60
    for (int sb = wid * 4; sb < SPS; sb += 16) {
        int s = sb + g;               // < 196 by coverage proof
        int base = (b * SPS + s) * 2;
        int ix = pxs[base] * 14 + pxs[base + 1];
        int iy = pys[base] * 14 + pys[base + 1];
        const float* lx = lds + cq * 197;
        unsigned int ux = 0, uy = 0;
        ux = __builtin_amdgcn_cvt_pk_fp8_f32(lx[ix],       lx[197 + ix], ux, false);
        ux = __builtin_amdgcn_cvt_pk_fp8_f32(lx[394 + ix], lx[591 + ix], ux, true);
        uy = __builtin_amdgcn_cvt_pk_fp8_f32(lx[iy],       lx[197 + iy], uy, false);
        uy = __builtin_amdgcn_cvt_pk_fp8_f32(lx[394 + iy], lx[591 + iy], uy, true);
        size_t ro = (size_t)(b * SPS + s) * K1;
        *(unsigned int*)(feats + ro + c0 + cq)        = ux;   // 64B coalesced per 16-lane group
        *(unsigned int*)(feats + ro + CHAN + c0 + cq) = uy;
    }
}

// ---------- 128x128 MX-fp8 K=128 GEMM: A via LDS (bank-floor swizzle), B in REGISTERS ----
// C = relu((A @ Bt^T)/64 + bias); A[M][K] fp8, Bt[N=512][K] fp8 (weights pre-scaled x64).
// Work remap: s = (bid&7)*(nwg/8) + bid>>3 -> A-sharing nTile blocks co-XCD, adjacent.
// A LDS tile [128 rows][128B]: 16B slot q holds global chunk q^(r&7) (R7's measured
// conflict-free geometry); frag = two aligned ds_read_b128 at slots (2lk+h)^(r&7)
// -> per instruction each 4-bank group serves exactly 8 lanes (theoretical floor).
// R12 BUGFIX: stageA now covers the FULL 128-row tile — 4 gload16/thread
// (256 thr x 4 x 16B = 16KB); R12's i<2 staged only rows 0..63 (absmax 38).
// B never touches LDS: per-lane rows are FIXED (wc,n,lr); per tile only k advances.
// B(t+1) prefetched into VGPRs during compute(t); the __syncthreads vmcnt drain makes
// both A(t+1) LDS and B(t+1) regs resident.  k-content of A and B frags both =
// bytes [32*lk, 32*lk+32) of their rows, in order -> symmetric -> exact product.
// predMode: pred = relu(h2)@W3, LDS-reduced, one atomic per (row,comp) (4 contenders).
__global__ __launch_bounds__(256, 2) void gemm_mx(const unsigned char* __restrict__ A,
                                                  const unsigned char* __restrict__ Bt,
                                                  const float* __restrict__ bias,
                                                  unsigned char* __restrict__ C,
                                                  const float* __restrict__ W3,
                                                  float* __restrict__ out,
                                                  int Kd, int predMode) {
    extern __shared__ char smem[];    // 2 x 16384 (A double buffer)
    const int t = threadIdx.x;
    const int wid = t >> 6, lane = t & 63;
    const int wr = wid >> 1, wc = wid & 1;       // 2x2 waves; wave owns 64x64
    const int lr = lane & 15, lk = lane >> 4;
    const int s = (blockIdx.x & 7) * (gridDim.x >> 3) + (blockIdx.x >> 3);
    const int mBase = (s >> 2) * 128;
    const int nBase = (s & 3) * 128;
    const int nK = Kd >> 7;                      // BK=128
    f32x4 acc[4][4] = {};

    // per-lane fixed B row pointers (32B-aligned: Kd multiple of 32)
    const unsigned char* bRow[4];
    #pragma unroll
    for (int n = 0; n < 4; ++n)
        bRow[n] = Bt + (size_t)(nBase + wc * 64 + n * 16 + lr) * Kd + lk * 32;

    // stage A K-tile td into buffer buf (16KB, 4 gload16/thread); inverse-swizzled src
    auto stageA = [&](int buf, int td) {
        char* Ab = smem + buf * 16384;
        int k0 = td << 7;
        #pragma unroll
        for (int i = 0; i < 4; ++i) {
            int lin = i * 256 + t;               // 0..1023 16B-units
            int row = lin >> 3;                  // 0..127  (full tile coverage)
            int cs  = (lin & 7) ^ (row & 7);     // 16B-granular swizzle (R7 pattern)
            gload_lds16((const char*)A + ((size_t)(mBase + row) * Kd + k0 + cs * 16),
                        Ab + lin * 16);
        }
    };
    auto loadB = [&](int8v (&dst)[4], int td) {
        #pragma unroll
        for (int n = 0; n < 4; ++n)
            dst[n] = *(const int8v*)(bRow[n] + (td << 7));
    };
    auto compute = [&](int buf, int8v (&bfr)[4]) {
        const char* Ab = smem + buf * 16384;
        int8v af[4];
        #pragma unroll
        for (int m = 0; m < 4; ++m) {
            int r = wr * 64 + m * 16 + lr;       // 0..127
            const char* p = Ab + r * 128;
            union { int4v h[2]; int8v v; } u;
            u.h[0] = *(const int4v*)(p + (((2 * lk + 0) ^ (r & 7)) * 16));
            u.h[1] = *(const int4v*)(p + (((2 * lk + 1) ^ (r & 7)) * 16));
            af[m] = u.v;
        }
        #pragma unroll
        for (int m = 0; m < 4; ++m)
            #pragma unroll
            for (int n = 0; n < 4; ++n)
                acc[m][n] = __builtin_amdgcn_mfma_scale_f32_16x16x128_f8f6f4(
                    af[m], bfr[n], acc[m][n], 0, 0, 0, SC1, 0, SC1);
    };

    int8v bfr[4], bnx[4];
    loadB(bfr, 0);
    stageA(0, 0);
    __syncthreads();                 // drains vmcnt: A(0) in LDS, B(0) in regs
    int cur = 0;
    for (int td = 0; td < nK; ++td) {
        if (td + 1 < nK) {
            stageA(cur ^ 1, td + 1); // A t+1 -> LDS, flies under compute
            loadB(bnx, td + 1);      // B t+1 -> regs, flies under compute
        }
        compute(cur, bfr);
        __syncthreads();             // drain: t+1 operands resident; LDS reuse safe
        if (td + 1 < nK) {
            #pragma unroll
            for (int n = 0; n < 4; ++n) bfr[n] = bnx[n];
        }
        cur ^= 1;
    }

    if (!predMode) {
        // epilogue: h1 = relu(acc/64 + b1) -> fp8.  C row=(lane>>4)*4+j, col=lane&15
        #pragma unroll
        for (int n = 0; n < 4; ++n) {
            int c = nBase + wc * 64 + n * 16 + lr;
            float bv = bias[c];
            #pragma unroll
            for (int m = 0; m < 4; ++m) {
                int r0 = mBase + wr * 64 + m * 16 + lk * 4;
                #pragma unroll
                for (int j = 0; j < 4; ++j)
                    C[(size_t)(r0 + j) * HID + c] = f2fp8(fmaxf(acc[m][n][j] * WINV + bv, 0.f));
            }
        }
    } else {
        // fused final layer: pred = relu(acc/64+b2) @ W3, LDS-reduced across wc waves
        float* red = (float*)smem;    // [128 rows][2 wc][2] = 2KB (main loop done)
        float w3v[4][2], bv[4];
        #pragma unroll
        for (int n = 0; n < 4; ++n) {
            int c = nBase + wc * 64 + n * 16 + lr;
            w3v[n][0] = W3[c * 2 + 0];
            w3v[n][1] = W3[c * 2 + 1];
            bv[n] = bias[c];
        }
        #pragma unroll
        for (int m = 0; m < 4; ++m) {
            #pragma unroll
            for (int j = 0; j < 4; ++j) {
                float p0 = 0.f, p1 = 0.f;
                #pragma unroll
                for (int n = 0; n < 4; ++n) {
                    float v = fmaxf(acc[m][n][j] * WINV + bv[n], 0.f);
                    p0 += v * w3v[n][0];
                    p1 += v * w3v[n][1];
                }
                #pragma unroll
                for (int msk = 1; msk < 16; msk <<= 1) {   // reduce over the 16 lr-lanes
                    p0 += __shfl_xor(p0, msk);
                    p1 += __shfl_xor(p1, msk);
                }
                if (lr == 0) {
                    int rl = wr * 64 + m * 16 + lk * 4 + j;    // 0..127, unique
                    red[rl * 4 + wc * 2 + 0] = p0;
                    red[rl * 4 + wc * 2 + 1] = p1;
                }
            }
        }
        __syncthreads();
        if (t < 256) {   // one (row, comp) per thread; 2-way sum; ONE atomic each
            int rl = t >> 1, comp = t & 1;
            float v = red[rl * 4 + 0 * 2 + comp] + red[rl * 4 + 1 * 2 + comp];
            atomicAdd(&out[(size_t)(mBase + rl) * 2 + comp], v);   // 4 contenders (nTiles)
        }
    }
}

// ---------- launch ----------
extern "C" void kernel_launch(void* const* d_in, const int* in_sizes, int n_in,
                              void* d_out, int out_size, void* d_ws, size_t ws_size,
                              hipStream_t stream) {
    const float* x  = (const float*)d_in[0];
    const float* W1 = (const float*)d_in[1];
    const float* b1 = (const float*)d_in[2];
    const float* W2 = (const float*)d_in[3];
    const float* b2 = (const float*)d_in[4];
    const float* W3 = (const float*)d_in[5];
    const float* b3 = (const float*)d_in[6];
    const int*  pxs = (const int*)d_in[7];
    const int*  pys = (const int*)d_in[8];
    float* out = (float*)d_out;
    char* ws = (char*)d_ws;

    // ws layout (bytes), fp8: W1t 786,432 | W2t 262,144 | h1 25,690,112 | feats 77,070,336
    unsigned char* W1t   = (unsigned char*)(ws + 0);
    unsigned char* W2t   = (unsigned char*)(ws + 786432);
    unsigned char* h1    = (unsigned char*)(ws + 1048576);
    unsigned char* feats = (unsigned char*)(ws + 26738688);   // end 103,809,024

    hipFuncSetAttribute((const void*)gemm_mx,
                        hipFuncAttributeMaxDynamicSharedMemorySize, 32768);

    transpose_cast_fp8<<<(K1 * HID + 255) / 256, 256, 0, stream>>>(W1, W1t, K1, HID);
    transpose_cast_fp8<<<(HID * HID + 255) / 256, 256, 0, stream>>>(W2, W2t, HID, HID);
    // gather also initializes out: pred rows = b3 (GEMM2 atomics accumulate), deltaxy written
    gather_feats<<<dim3(12, BATCH), 256, 0, stream>>>(x, pxs, pys, b3, feats, out);
    // GEMM1: h1 = relu(feats @ (64*W1t)^T /64 + b1)   grid = 392 mTiles * 4 nTiles = 1568
    gemm_mx<<<(MROWS / 128) * 4, 256, 32768, stream>>>(
        feats, W1t, b1, h1, nullptr, nullptr, K1, 0);
    // GEMM2 (+fused GEMM3): out[0:2M) += relu(h1 @ (64*W2t)^T /64 + b2) @ W3
    gemm_mx<<<(MROWS / 128) * 4, 256, 32768, stream>>>(
        h1, W2t, b2, nullptr, W3, out, HID, 1);
}

// Round 14
// 180.209 us; speedup vs baseline: 1.2900x; 1.2900x over previous
//
#include <hip/hip_runtime.h>
#include <hip/hip_bf16.h>

// ---------- types / helpers ----------
typedef __attribute__((ext_vector_type(4))) float f32x4;   // MFMA C/D frag
typedef __attribute__((ext_vector_type(4))) int   int4v;   // one 16B load
typedef __attribute__((ext_vector_type(8))) int   int8v;   // K=128 fp8 A/B frag (32B)

// float -> OCP e4m3fn byte (RNE on normals, RN on subnormals, saturate to 448)
// (cold path: weight prep + GEMM epilogue; gather hot path uses HW v_cvt_pk_fp8_f32)
__device__ __forceinline__ unsigned char f2fp8(float f) {
    unsigned char s = (__float_as_uint(f) >> 24) & 0x80;
    float a = fabsf(f);
    if (a >= 448.f) return s | 0x7E;
    if (a < 0.015625f) {                       // subnormal: step 2^-9
        int q = (int)(a * 512.0f + 0.5f);
        return s | (unsigned char)q;
    }
    unsigned int u = __float_as_uint(a);
    u += 0x0007FFFF + ((u >> 20) & 1);         // RNE to 3 mantissa bits (carry-safe)
    int e8 = (int)((u >> 23) & 0xFF) - 120;    // -127+7
    if (e8 >= 16) return s | 0x7E;
    return s | (unsigned char)((e8 << 3) | ((u >> 20) & 7));
}
__device__ __forceinline__ void gload_lds16(const void* g, void* l) {
    // async global->LDS, 16B/lane; LDS dest = wave-uniform base + lane*16
    __builtin_amdgcn_global_load_lds((const __attribute__((address_space(1))) void*)g,
                                     (__attribute__((address_space(3))) void*)l, 16, 0, 0);
}

// ---------- constants ----------
#define BATCH 256
#define CHAN  768
#define HW    196
#define SPS   196
#define HID   512
#define MROWS 50176   // BATCH*SPS
#define K1    1536    // 2*CHAN
#define WSCL  64.0f           // weights pre-scaled by 64 (e4m3 subnormal dodge)
#define WINV  0.015625f       // 1/64 applied in epilogue
#define SC1   0x7F7F7F7F      // E8M0 scale 1.0 in every byte (mapping-invariant)

// ---------- weight prep: in [K][N] fp32 -> out [N][K] fp8 of (w * 64) ----------
__global__ void transpose_cast_fp8(const float* __restrict__ in, unsigned char* __restrict__ out,
                                   int K, int N) {
    int idx = blockIdx.x * 256 + threadIdx.x;
    if (idx >= K * N) return;
    int n = idx / K, k = idx - n * K;
    out[idx] = f2fp8(in[(size_t)k * N + n] * WSCL);
}

// ---------- gather + out-init: feats fp8 via HW cvt_pk; 4B packed stores (R11, proven) ----------
__global__ __launch_bounds__(256) void gather_feats(const float* __restrict__ x,
                                                    const int* __restrict__ pxs,
                                                    const int* __restrict__ pys,
                                                    const float* __restrict__ b3,
                                                    unsigned char* __restrict__ feats,
                                                    float* __restrict__ out) {
    __shared__ float lds[64 * 197];   // pitch 197: stride-5 banks, conflict-free
    int chunk = blockIdx.x;           // 0..11 (64-channel chunk)
    int b     = blockIdx.y;           // 0..255
    int c0 = chunk * 64;
    const float* xb = x + ((size_t)b * CHAN + c0) * HW;
    for (int t = threadIdx.x; t < 64 * HW; t += 256) {
        int j = t / HW, p = t - j * HW;
        lds[j * 197 + p] = xb[t];     // coalesced read of 64 full channels
    }
    if (chunk == 0) {                 // per-batch: init pred rows to b3, write deltaxy
        float b30 = b3[0], b31 = b3[1];
        for (int i = threadIdx.x; i < SPS * 2; i += 256) {
            int idx = b * SPS * 2 + i;
            out[idx] = (i & 1) ? b31 : b30;                          // pred init (atomics add on top)
            out[MROWS * 2 + idx] = (float)(pxs[idx] - pys[idx]) + 13.0f;  // (H-1)=13
        }
    }
    __syncthreads();
    int wid = threadIdx.x >> 6, lane = threadIdx.x & 63;
    int g = lane >> 4;                // s-offset within the 4-s pack
    int cq = (lane & 15) * 4;         // channel quad 0,4,..,60
    for (int sb = wid * 4; sb < SPS; sb += 16) {
        int s = sb + g;               // < 196 by coverage proof
        int base = (b * SPS + s) * 2;
        int ix = pxs[base] * 14 + pxs[base + 1];
        int iy = pys[base] * 14 + pys[base + 1];
        const float* lx = lds + cq * 197;
        unsigned int ux = 0, uy = 0;
        ux = __builtin_amdgcn_cvt_pk_fp8_f32(lx[ix],       lx[197 + ix], ux, false);
        ux = __builtin_amdgcn_cvt_pk_fp8_f32(lx[394 + ix], lx[591 + ix], ux, true);
        uy = __builtin_amdgcn_cvt_pk_fp8_f32(lx[iy],       lx[197 + iy], uy, false);
        uy = __builtin_amdgcn_cvt_pk_fp8_f32(lx[394 + iy], lx[591 + iy], uy, true);
        size_t ro = (size_t)(b * SPS + s) * K1;
        *(unsigned int*)(feats + ro + c0 + cq)        = ux;   // 64B coalesced per 16-lane group
        *(unsigned int*)(feats + ro + CHAN + c0 + cq) = uy;
    }
}

// ---------- 128x128 MX-fp8 K=128 GEMM: R11 dbuf skeleton + 16B ^(r&7) swizzle, no remap ----
// C = relu((A @ Bt^T)/64 + bias); A[M][K] fp8, Bt[N=512][K] fp8 (weights pre-scaled x64).
// Grid 1-D plain bid (nTile fastest -> A-sharers temporally adjacent, L2/L3 natural
// sharing; R2 evidence: no-remap had the highest HBM BW, R3/R11's remap hurt).
// LDS tile [128 rows][128B]: 16B slot q holds global chunk q^(r&7) (R7/R13-measured
// conflict-free geometry: per b128 instruction each bank serves 2 lanes = free).
// Frag = two aligned ds_read_b128 at slots (2lk+h)^(r&7), h=0,1 -> bytes
// [32lk, 32lk+32) of the row for BOTH A and B (symmetric k-mapping -> exact).
// predMode: pred = relu(h2)@W3, LDS-reduced, one atomic per (row,comp) (4 contenders).
__global__ __launch_bounds__(256, 2) void gemm_mx(const unsigned char* __restrict__ A,
                                                  const unsigned char* __restrict__ Bt,
                                                  const float* __restrict__ bias,
                                                  unsigned char* __restrict__ C,
                                                  const float* __restrict__ W3,
                                                  float* __restrict__ out,
                                                  int Kd, int predMode) {
    extern __shared__ char smem[];    // 2 x (A 16KB + B 16KB) = 65536
    const int t = threadIdx.x;
    const int wid = t >> 6, lane = t & 63;
    const int wr = wid >> 1, wc = wid & 1;       // 2x2 waves; wave owns 64x64
    const int lr = lane & 15, lk = lane >> 4;
    const int mBase = (blockIdx.x >> 2) * 128;
    const int nBase = (blockIdx.x & 3) * 128;
    const int nK = Kd >> 7;                      // BK=128
    f32x4 acc[4][4] = {};

    // stage K-tile td into buffer buf: A 16KB + B 16KB, 8 gload16/thread; inverse-swizzled src
    auto stage = [&](int buf, int td) {
        char* Ab = smem + buf * 32768;
        char* Bb = Ab + 16384;
        int k0 = td << 7;
        #pragma unroll
        for (int i = 0; i < 4; ++i) {
            int lin = i * 256 + t;               // 0..1023 16B-units
            int row = lin >> 3;                  // 0..127
            int cs  = (lin & 7) ^ (row & 7);     // 16B-granular swizzle (conflict-free)
            gload_lds16((const char*)A + ((size_t)(mBase + row) * Kd + k0 + cs * 16),
                        Ab + lin * 16);
        }
        #pragma unroll
        for (int i = 0; i < 4; ++i) {
            int lin = i * 256 + t;
            int row = lin >> 3;
            int cs  = (lin & 7) ^ (row & 7);
            gload_lds16((const char*)Bt + ((size_t)(nBase + row) * Kd + k0 + cs * 16),
                        Bb + lin * 16);
        }
    };
    auto compute = [&](int buf) {
        const char* Ab = smem + buf * 32768;
        const char* Bb = Ab + 16384;
        int8v af[4], bfr[4];
        #pragma unroll
        for (int m = 0; m < 4; ++m) {
            int r = wr * 64 + m * 16 + lr;       // 0..127
            const char* p = Ab + r * 128;
            union { int4v h[2]; int8v v; } u;
            u.h[0] = *(const int4v*)(p + (((2 * lk + 0) ^ (r & 7)) * 16));
            u.h[1] = *(const int4v*)(p + (((2 * lk + 1) ^ (r & 7)) * 16));
            af[m] = u.v;
        }
        #pragma unroll
        for (int n = 0; n < 4; ++n) {
            int r = wc * 64 + n * 16 + lr;
            const char* p = Bb + r * 128;
            union { int4v h[2]; int8v v; } u;
            u.h[0] = *(const int4v*)(p + (((2 * lk + 0) ^ (r & 7)) * 16));
            u.h[1] = *(const int4v*)(p + (((2 * lk + 1) ^ (r & 7)) * 16));
            bfr[n] = u.v;
        }
        #pragma unroll
        for (int m = 0; m < 4; ++m)
            #pragma unroll
            for (int n = 0; n < 4; ++n)
                acc[m][n] = __builtin_amdgcn_mfma_scale_f32_16x16x128_f8f6f4(
                    af[m], bfr[n], acc[m][n], 0, 0, 0, SC1, 0, SC1);
    };

    stage(0, 0);
    __syncthreads();                 // compiler drains vmcnt before barrier
    int cur = 0;
    for (int td = 0; td < nK; ++td) {
        if (td + 1 < nK) stage(cur ^ 1, td + 1);   // flies under compute(td)
        compute(cur);
        __syncthreads();
        cur ^= 1;
    }

    if (!predMode) {
        // epilogue: h1 = relu(acc/64 + b1) -> fp8.  C row=(lane>>4)*4+j, col=lane&15
        #pragma unroll
        for (int n = 0; n < 4; ++n) {
            int c = nBase + wc * 64 + n * 16 + lr;
            float bv = bias[c];
            #pragma unroll
            for (int m = 0; m < 4; ++m) {
                int r0 = mBase + wr * 64 + m * 16 + lk * 4;
                #pragma unroll
                for (int j = 0; j < 4; ++j)
                    C[(size_t)(r0 + j) * HID + c] = f2fp8(fmaxf(acc[m][n][j] * WINV + bv, 0.f));
            }
        }
    } else {
        // fused final layer: pred = relu(acc/64+b2) @ W3, LDS-reduced across wc waves
        float* red = (float*)smem;    // [128 rows][2 wc][2] = 2KB (main loop done)
        float w3v[4][2], bv[4];
        #pragma unroll
        for (int n = 0; n < 4; ++n) {
            int c = nBase + wc * 64 + n * 16 + lr;
            w3v[n][0] = W3[c * 2 + 0];
            w3v[n][1] = W3[c * 2 + 1];
            bv[n] = bias[c];
        }
        #pragma unroll
        for (int m = 0; m < 4; ++m) {
            #pragma unroll
            for (int j = 0; j < 4; ++j) {
                float p0 = 0.f, p1 = 0.f;
                #pragma unroll
                for (int n = 0; n < 4; ++n) {
                    float v = fmaxf(acc[m][n][j] * WINV + bv[n], 0.f);
                    p0 += v * w3v[n][0];
                    p1 += v * w3v[n][1];
                }
                #pragma unroll
                for (int msk = 1; msk < 16; msk <<= 1) {   // reduce over the 16 lr-lanes
                    p0 += __shfl_xor(p0, msk);
                    p1 += __shfl_xor(p1, msk);
                }
                if (lr == 0) {
                    int rl = wr * 64 + m * 16 + lk * 4 + j;    // 0..127, unique
                    red[rl * 4 + wc * 2 + 0] = p0;
                    red[rl * 4 + wc * 2 + 1] = p1;
                }
            }
        }
        __syncthreads();
        if (t < 256) {   // one (row, comp) per thread; 2-way sum; ONE atomic each
            int rl = t >> 1, comp = t & 1;
            float v = red[rl * 4 + 0 * 2 + comp] + red[rl * 4 + 1 * 2 + comp];
            atomicAdd(&out[(size_t)(mBase + rl) * 2 + comp], v);   // 4 contenders (nTiles)
        }
    }
}

// ---------- launch ----------
extern "C" void kernel_launch(void* const* d_in, const int* in_sizes, int n_in,
                              void* d_out, int out_size, void* d_ws, size_t ws_size,
                              hipStream_t stream) {
    const float* x  = (const float*)d_in[0];
    const float* W1 = (const float*)d_in[1];
    const float* b1 = (const float*)d_in[2];
    const float* W2 = (const float*)d_in[3];
    const float* b2 = (const float*)d_in[4];
    const float* W3 = (const float*)d_in[5];
    const float* b3 = (const float*)d_in[6];
    const int*  pxs = (const int*)d_in[7];
    const int*  pys = (const int*)d_in[8];
    float* out = (float*)d_out;
    char* ws = (char*)d_ws;

    // ws layout (bytes), fp8: W1t 786,432 | W2t 262,144 | h1 25,690,112 | feats 77,070,336
    unsigned char* W1t   = (unsigned char*)(ws + 0);
    unsigned char* W2t   = (unsigned char*)(ws + 786432);
    unsigned char* h1    = (unsigned char*)(ws + 1048576);
    unsigned char* feats = (unsigned char*)(ws + 26738688);   // end 103,809,024

    hipFuncSetAttribute((const void*)gemm_mx,
                        hipFuncAttributeMaxDynamicSharedMemorySize, 65536);

    transpose_cast_fp8<<<(K1 * HID + 255) / 256, 256, 0, stream>>>(W1, W1t, K1, HID);
    transpose_cast_fp8<<<(HID * HID + 255) / 256, 256, 0, stream>>>(W2, W2t, HID, HID);
    // gather also initializes out: pred rows = b3 (GEMM2 atomics accumulate), deltaxy written
    gather_feats<<<dim3(12, BATCH), 256, 0, stream>>>(x, pxs, pys, b3, feats, out);
    // GEMM1: h1 = relu(feats @ (64*W1t)^T /64 + b1)   grid = 392 mTiles * 4 nTiles = 1568
    gemm_mx<<<(MROWS / 128) * 4, 256, 65536, stream>>>(
        feats, W1t, b1, h1, nullptr, nullptr, K1, 0);
    // GEMM2 (+fused GEMM3): out[0:2M) += relu(h1 @ (64*W2t)^T /64 + b2) @ W3
    gemm_mx<<<(MROWS / 128) * 4, 256, 65536, stream>>>(
        h1, W2t, b2, nullptr, W3, out, HID, 1);
}